// Round 13
// baseline (232.676 us; speedup 1.0000x reference)
//
#include <hip/hip_runtime.h>
#include <hip/hip_bf16.h>

#define N_NODES 100000
#define N_EDGES 1600000
#define IN_DIM  128
#define HID     64

#define NGROUPS 8
#define NPG     ((N_NODES + NGROUPS - 1) / NGROUPS)   // 12500 nodes per XCD group
#define PSTRIDE 48
// phase A (edge bucketing)
#define PREA_BLKS 800
#define EPBA      (N_EDGES / PREA_BLKS)               // 2000 edges per block
#define PRE_BLKS  (PREA_BLKS + 48)                    // + W-prep blocks
#define BCAP      204800                              // per-bucket capacity (mean 200K, +11 sigma)
// phase B (XCD-local scatter) + GEMM1 in k_mega
#define FILL_BLKS  1024                               // prefix -> bid&7 == XCD
#define GEMM1_BLKS 782

typedef __attribute__((ext_vector_type(8))) short bf16x8;
typedef __attribute__((ext_vector_type(4))) float f32x4;
typedef __attribute__((ext_vector_type(8))) float f32x8;
typedef __attribute__((ext_vector_type(4))) int   i32x4;
typedef __attribute__((ext_vector_type(2))) unsigned u32x2;

__device__ inline unsigned short f2bf_u(float x) {
    __hip_bfloat16 h = __float2bfloat16(x);
    return __builtin_bit_cast(unsigned short, h);
}
__device__ inline float bfu2f(unsigned short u) {
    unsigned v = ((unsigned)u) << 16;
    return __builtin_bit_cast(float, v);
}

// ---------------- W prep helper ----------------
__device__ inline void prep_pack(const float* __restrict__ Wl,
                                 const float* __restrict__ Wr,
                                 ushort2* __restrict__ Bhi,
                                 ushort2* __restrict__ Blo, int idx) {
    int j  = idx & 3;
    int l  = (idx >> 2) & 63;
    int c  = (idx >> 8) & 7;
    int kt = idx >> 11;
    int col = c * 16 + (l & 15);
    int k0  = kt * 32 + (l >> 4) * 8 + 2 * j;
    const float* W = (col < 64) ? Wl : Wr;
    int cc = col & 63;
    float w0 = W[(size_t)k0 * 64 + cc];
    float w1 = W[(size_t)(k0 + 1) * 64 + cc];
    unsigned short h0 = f2bf_u(w0), h1 = f2bf_u(w1);
    unsigned short lo0 = f2bf_u(w0 - bfu2f(h0)), lo1 = f2bf_u(w1 - bfu2f(h1));
    Bhi[idx] = make_ushort2(h0, h1);
    Blo[idx] = make_ushort2(lo0, lo1);
}

// ---------------- k_pre: phase A (edge bucketing, edges read ONCE) + W prep ----------
// Each phase-A block: LDS histogram over 8 dst-range buckets -> ONE bulk global
// reservation per bucket -> ballot-ranked direct writes of (d,s) into contiguous
// per-bucket segments (each wave writes ~8 full 64B lines per bucket).
__global__ __launch_bounds__(256) void k_pre(const int* __restrict__ ei,
                                             int* __restrict__ gcnt,
                                             uint2* __restrict__ ebuf,
                                             const float* __restrict__ W1l,
                                             const float* __restrict__ W1r,
                                             const float* __restrict__ W2l,
                                             const float* __restrict__ W2r,
                                             ushort2* __restrict__ Bh1,
                                             ushort2* __restrict__ Bl1,
                                             ushort2* __restrict__ Bh2,
                                             ushort2* __restrict__ Bl2) {
    if (blockIdx.x >= PREA_BLKS) {
        int bb = blockIdx.x - PREA_BLKS;
        if (bb < 32) prep_pack(W1l, W1r, Bh1, Bl1, bb * 256 + threadIdx.x);
        else         prep_pack(W2l, W2r, Bh2, Bl2, (bb - 32) * 256 + threadIdx.x);
        return;
    }
    __shared__ int hist[8], gbase[8], lcur[8];
    const int tid  = threadIdx.x;
    const int lane = tid & 63;
    if (tid < 8) { hist[tid] = 0; lcur[tid] = 0; }
    __syncthreads();
    const int start = blockIdx.x * EPBA;
    const int end   = start + EPBA;
    const int* __restrict__ src = ei;
    const int* __restrict__ dst = ei + N_EDGES;
    // pass 1: histogram
    for (int i = start + tid; i < end; i += 256) {
        int d = __builtin_nontemporal_load(dst + i);
        atomicAdd(&hist[d / NPG], 1);
    }
    __syncthreads();
    if (tid < 8) gbase[tid] = atomicAdd(&gcnt[tid], hist[tid]);
    __syncthreads();
    // pass 2: ballot-ranked writes (chunk is L2-hot from pass 1)
    for (int i = start + tid; i < end; i += 256) {
        int d = dst[i];
        int s = src[i];
        int b = d / NPG;
#pragma unroll
        for (int bb = 0; bb < 8; ++bb) {
            unsigned long long mask = __ballot(b == bb);
            if (mask == 0) continue;
            int first = __ffsll(mask) - 1;
            int base = 0;
            if (lane == first) base = atomicAdd(&lcur[bb], (int)__popcll(mask));
            base = __shfl(base, first, 64);
            if (b == bb) {
                int r = gbase[bb] + base + (int)__popcll(mask & ((1ull << lane) - 1));
                if (r < BCAP) ebuf[(size_t)bb * BCAP + r] = make_uint2((unsigned)d, (unsigned)s);
            }
        }
    }
}

// ---------------- MEGA: phase-B scatter (1024 prefix, XCD-local) || GEMM1 ------------
__global__ __launch_bounds__(256) void k_mega(const float* __restrict__ X,
                                              const i32x4* __restrict__ Bhi,
                                              const i32x4* __restrict__ Blo,
                                              const float* __restrict__ bias,
                                              unsigned short* __restrict__ Ybf,
                                              unsigned short* __restrict__ Dbf,
                                              const int* __restrict__ gcnt,
                                              const u32x2* __restrict__ ebuf,
                                              int* __restrict__ cur,
                                              int* __restrict__ adj, int n) {
    if (blockIdx.x < FILL_BLKS) {
        const int g = blockIdx.x & (NGROUPS - 1);     // == XCD id (prefix dispatch)
        const int k = blockIdx.x >> 3;                // 0..127
        const int cnt = min(gcnt[g], BCAP);
        const int chunk = (cnt + 127) >> 7;
        const int s0 = k * chunk;
        const int s1 = min(cnt, s0 + chunk);
        const u32x2* __restrict__ eb = ebuf + (size_t)g * BCAP;
        for (int i = s0 + threadIdx.x; i < s1; i += 256) {
            u32x2 p = __builtin_nontemporal_load(eb + i);
            int d = (int)p[0];
            int pos = atomicAdd(&cur[d], 1);
            if (pos < PSTRIDE) adj[d * PSTRIDE + pos] = (int)p[1];
        }
        return;
    }
    // ---- gemm1 body ----
    const int K = IN_DIM;
    const int gb   = blockIdx.x - FILL_BLKS;
    const int lane = threadIdx.x & 63;
    const int wid  = threadIdx.x >> 6;
    const int m0   = (gb * 4 + wid) * 32;
    if (m0 >= n) return;
    const int r  = lane & 15;
    const int kg = lane >> 4;

    f32x4 acc[2][8];
#pragma unroll
    for (int mt = 0; mt < 2; ++mt)
#pragma unroll
        for (int c = 0; c < 8; ++c) acc[mt][c] = (f32x4)(0.f);

#pragma unroll
    for (int kt = 0; kt < K / 32; ++kt) {
        bf16x8 ah[2], al[2];
#pragma unroll
        for (int mt = 0; mt < 2; ++mt) {
            const f32x4* p = (const f32x4*)(X + (size_t)(m0 + mt * 16 + r) * K + kt * 32 + kg * 8);
            f32x4 x0 = __builtin_nontemporal_load(p);
            f32x4 x1 = __builtin_nontemporal_load(p + 1);
            float xv[8];
#pragma unroll
            for (int t = 0; t < 4; ++t) { xv[t] = x0[t]; xv[4 + t] = x1[t]; }
#pragma unroll
            for (int t = 0; t < 8; ++t) {
                unsigned short h = f2bf_u(xv[t]);
                ah[mt][t] = (short)h;
                al[mt][t] = (short)f2bf_u(xv[t] - bfu2f(h));
            }
        }
#pragma unroll
        for (int c = 0; c < 8; ++c) {
            const int bi = (kt * 8 + c) * 64 + lane;
            bf16x8 bh = __builtin_bit_cast(bf16x8, Bhi[bi]);
            bf16x8 bl = __builtin_bit_cast(bf16x8, Blo[bi]);
#pragma unroll
            for (int mt = 0; mt < 2; ++mt) {
                acc[mt][c] = __builtin_amdgcn_mfma_f32_16x16x32_bf16(ah[mt], bh, acc[mt][c], 0, 0, 0);
                acc[mt][c] = __builtin_amdgcn_mfma_f32_16x16x32_bf16(ah[mt], bl, acc[mt][c], 0, 0, 0);
                acc[mt][c] = __builtin_amdgcn_mfma_f32_16x16x32_bf16(al[mt], bh, acc[mt][c], 0, 0, 0);
            }
        }
    }
#pragma unroll
    for (int mt = 0; mt < 2; ++mt) {
#pragma unroll
        for (int c = 0; c < 8; ++c) {
            int col = c * 16 + r;
            float badd = (c >= 4) ? bias[col - 64] : 0.f;
#pragma unroll
            for (int j = 0; j < 4; ++j) {
                int row = m0 + mt * 16 + kg * 4 + j;
                if (row < n) {
                    if (c < 4) Ybf[(size_t)row * 64 + col] = f2bf_u(acc[mt][c][j]);
                    else       Dbf[(size_t)row * 64 + col - 64] = f2bf_u(acc[mt][c][j] + badd);
                }
            }
        }
    }
}

// ---------------- fused agg1 + gemm2: block = 32 nodes; 16B/lane gathers --------------
__global__ __launch_bounds__(256) void k_agg1f(const unsigned short* __restrict__ Abf,
                                               unsigned short* __restrict__ Dbf,
                                               const int* __restrict__ adj,
                                               const int* __restrict__ deg,
                                               const i32x4* __restrict__ Bhi,
                                               const i32x4* __restrict__ Blo,
                                               const float* __restrict__ bias,
                                               unsigned short* __restrict__ Bbf) {
    __shared__ unsigned short hs[32][72];
    const int lane = threadIdx.x & 63;
    const int wv   = threadIdx.x >> 6;
    const int v0   = blockIdx.x * 32;
    const int c = lane & 7;
    const int j = lane >> 3;
    const bf16x8* __restrict__ A8 = (const bf16x8*)Abf;

    for (int t = 0; t < 8; ++t) {
        const int v = v0 + wv * 8 + t;
        const int s = v * PSTRIDE;
        const int dgf = deg[v];
        const int d = min(dgf, PSTRIDE);
        const float iv = 1.0f / (float)max(dgf, 1);
        const int uall = (lane < d) ? adj[s + lane] : 0;
        f32x8 acc = (f32x8)(0.f);
        const int nit = (d + 7) >> 3;
        for (int it = 0; it < nit; ++it) {
            const int nb = it * 8 + j;
            const int u = __shfl(uall, nb, 64);
            if (nb < d) {
                bf16x8 m = A8[(size_t)u * 8 + c];
#pragma unroll
                for (int q = 0; q < 8; ++q) acc[q] += bfu2f((unsigned short)m[q]);
            }
        }
#pragma unroll
        for (int msk = 8; msk <= 32; msk <<= 1) {
#pragma unroll
            for (int q = 0; q < 8; ++q) acc[q] += __shfl_xor(acc[q], msk, 64);
        }
        if (j == 0) {
            bf16x8 zb = ((const bf16x8*)Dbf)[(size_t)v * 8 + c];
            bf16x8 hb;
#pragma unroll
            for (int q = 0; q < 8; ++q)
                hb[q] = (short)f2bf_u(fmaxf(fmaf(acc[q], iv, bfu2f((unsigned short)zb[q])), 0.f));
            *(bf16x8*)&hs[wv * 8 + t][c * 8] = hb;
        }
    }
    __syncthreads();
    const int r  = lane & 15;
    const int kg = lane >> 4;
    f32x4 acc2[2][2];
#pragma unroll
    for (int mt = 0; mt < 2; ++mt)
#pragma unroll
        for (int ci = 0; ci < 2; ++ci) acc2[mt][ci] = (f32x4)(0.f);
#pragma unroll
    for (int kt = 0; kt < 2; ++kt) {
        bf16x8 ah[2];
#pragma unroll
        for (int mt = 0; mt < 2; ++mt)
            ah[mt] = *(const bf16x8*)&hs[mt * 16 + r][kt * 32 + kg * 8];
#pragma unroll
        for (int ci = 0; ci < 2; ++ci) {
            const int cg = wv * 2 + ci;
            const int bi = (kt * 8 + cg) * 64 + lane;
            bf16x8 bh = __builtin_bit_cast(bf16x8, Bhi[bi]);
            bf16x8 bl = __builtin_bit_cast(bf16x8, Blo[bi]);
#pragma unroll
            for (int mt = 0; mt < 2; ++mt) {
                acc2[mt][ci] = __builtin_amdgcn_mfma_f32_16x16x32_bf16(ah[mt], bh, acc2[mt][ci], 0, 0, 0);
                acc2[mt][ci] = __builtin_amdgcn_mfma_f32_16x16x32_bf16(ah[mt], bl, acc2[mt][ci], 0, 0, 0);
            }
        }
    }
#pragma unroll
    for (int mt = 0; mt < 2; ++mt) {
#pragma unroll
        for (int ci = 0; ci < 2; ++ci) {
            const int cg = wv * 2 + ci;
            const int col = cg * 16 + r;
            const float badd = (cg >= 4) ? bias[col - 64] : 0.f;
#pragma unroll
            for (int jj = 0; jj < 4; ++jj) {
                const int row = v0 + mt * 16 + kg * 4 + jj;
                if (cg < 4) Bbf[(size_t)row * 64 + col] = f2bf_u(acc2[mt][ci][jj]);
                else        Dbf[(size_t)row * 64 + col - 64] = f2bf_u(acc2[mt][ci][jj] + badd);
            }
        }
    }
}

// ---------------- final agg: out = relu(sum(Bbf[adj])/deg + Dbf) @ Wc + bc ------------
__global__ __launch_bounds__(256) void k_agg2(const unsigned short* __restrict__ Abf,
                                              const unsigned short* __restrict__ Zbf,
                                              const int* __restrict__ adj,
                                              const int* __restrict__ deg,
                                              const float* __restrict__ Wc,
                                              const float* __restrict__ bc,
                                              float* __restrict__ out, int n) {
    const int lane = threadIdx.x & 63;
    const int wv = threadIdx.x >> 6;
    const int v = blockIdx.x * 4 + wv;
    if (v >= n) return;
    const int c = lane & 7;
    const int j = lane >> 3;
    const int s = v * PSTRIDE;
    const int dgf = deg[v];
    const int d = min(dgf, PSTRIDE);
    const float iv = 1.0f / (float)max(dgf, 1);
    const int uall = (lane < d) ? adj[s + lane] : 0;
    f32x8 acc = (f32x8)(0.f);
    const bf16x8* __restrict__ A8 = (const bf16x8*)Abf;
    const int nit = (d + 7) >> 3;
    for (int it = 0; it < nit; ++it) {
        const int nb = it * 8 + j;
        const int u = __shfl(uall, nb, 64);
        if (nb < d) {
            bf16x8 m = A8[(size_t)u * 8 + c];
#pragma unroll
            for (int q = 0; q < 8; ++q) acc[q] += bfu2f((unsigned short)m[q]);
        }
    }
#pragma unroll
    for (int msk = 8; msk <= 32; msk <<= 1) {
#pragma unroll
        for (int q = 0; q < 8; ++q) acc[q] += __shfl_xor(acc[q], msk, 64);
    }
    bf16x8 zb = ((const bf16x8*)Zbf)[(size_t)v * 8 + c];
    const float4* Wc4 = (const float4*)Wc;
    float4 w0 = Wc4[c * 2], w1 = Wc4[c * 2 + 1];
    float h;
    float pv = 0.f;
    h = fmaxf(fmaf(acc[0], iv, bfu2f((unsigned short)zb[0])), 0.f); pv += h * w0.x;
    h = fmaxf(fmaf(acc[1], iv, bfu2f((unsigned short)zb[1])), 0.f); pv += h * w0.y;
    h = fmaxf(fmaf(acc[2], iv, bfu2f((unsigned short)zb[2])), 0.f); pv += h * w0.z;
    h = fmaxf(fmaf(acc[3], iv, bfu2f((unsigned short)zb[3])), 0.f); pv += h * w0.w;
    h = fmaxf(fmaf(acc[4], iv, bfu2f((unsigned short)zb[4])), 0.f); pv += h * w1.x;
    h = fmaxf(fmaf(acc[5], iv, bfu2f((unsigned short)zb[5])), 0.f); pv += h * w1.y;
    h = fmaxf(fmaf(acc[6], iv, bfu2f((unsigned short)zb[6])), 0.f); pv += h * w1.z;
    h = fmaxf(fmaf(acc[7], iv, bfu2f((unsigned short)zb[7])), 0.f); pv += h * w1.w;
#pragma unroll
    for (int msk = 1; msk <= 4; msk <<= 1) pv += __shfl_xor(pv, msk, 64);
    if (lane == 0) out[v] = pv + bc[0];
}

extern "C" void kernel_launch(void* const* d_in, const int* in_sizes, int n_in,
                              void* d_out, int out_size, void* d_ws, size_t ws_size,
                              hipStream_t stream) {
    const float* x   = (const float*)d_in[0];
    const int*   ei  = (const int*)d_in[1];
    const float* W1l = (const float*)d_in[2];
    const float* W1r = (const float*)d_in[3];
    const float* b1  = (const float*)d_in[4];
    const float* W2l = (const float*)d_in[5];
    const float* W2r = (const float*)d_in[6];
    const float* b2  = (const float*)d_in[7];
    const float* Wc  = (const float*)d_in[8];
    const float* bc  = (const float*)d_in[9];
    float* out = (float*)d_out;

    char* w = (char*)d_ws;
    auto carve = [&](size_t bytes) -> void* {
        void* p = (void*)w;
        w += (bytes + 255) & ~(size_t)255;
        return p;
    };
    int*   gcnt = (int*)carve(32);                                    // 8 bucket counters
    int*   cur  = (int*)carve((size_t)N_NODES * 4);                   // contiguous after gcnt
    int*   adj  = (int*)carve(((size_t)N_NODES * PSTRIDE + 64) * 4);
    unsigned short* Abf = (unsigned short*)carve((size_t)N_NODES * HID * 2);
    unsigned short* Bbf = (unsigned short*)carve((size_t)N_NODES * HID * 2);
    unsigned short* Dbf = (unsigned short*)carve((size_t)N_NODES * HID * 2);
    uint2* ebuf = (uint2*)carve((size_t)NGROUPS * BCAP * 8);          // 13.1 MB bucketed edges
    ushort2* Bh1 = (ushort2*)carve((size_t)(IN_DIM / 32) * 8 * 64 * 4 * 4);
    ushort2* Bl1 = (ushort2*)carve((size_t)(IN_DIM / 32) * 8 * 64 * 4 * 4);
    ushort2* Bh2 = (ushort2*)carve((size_t)(HID / 32) * 8 * 64 * 4 * 4);
    ushort2* Bl2 = (ushort2*)carve((size_t)(HID / 32) * 8 * 64 * 4 * 4);

    // gcnt (256B slot) and cur are contiguous: one memset
    hipMemsetAsync(gcnt, 0, 256 + (size_t)N_NODES * 4, stream);

    // phase A bucketing + W prep (one launch)
    k_pre<<<PRE_BLKS, 256, 0, stream>>>(ei, gcnt, ebuf, W1l, W1r, W2l, W2r, Bh1, Bl1, Bh2, Bl2);

    // phase B XCD-local scatter (prefix) || GEMM1
    k_mega<<<FILL_BLKS + GEMM1_BLKS, 256, 0, stream>>>(
        x, (const i32x4*)Bh1, (const i32x4*)Bl1, b1, Abf, Dbf,
        gcnt, (const u32x2*)ebuf, cur, adj, N_NODES);

    // fused agg1 + gemm2
    k_agg1f<<<N_NODES / 32, 256, 0, stream>>>(Abf, Dbf, adj, cur,
                                              (const i32x4*)Bh2, (const i32x4*)Bl2, b2, Bbf);

    k_agg2<<<N_NODES / 4, 256, 0, stream>>>(Bbf, Dbf, adj, cur, Wc, bc, out, N_NODES);
}

// Round 14
// 179.117 us; speedup vs baseline: 1.2990x; 1.2990x over previous
//
#include <hip/hip_runtime.h>
#include <hip/hip_bf16.h>

#define N_NODES 100000
#define N_EDGES 1600000
#define IN_DIM  128
#define HID     64

#define PSTRIDE 48
// phase A: bucket edges by dst>>8 (391 buckets of 256 nodes)
#define NBKT      391
#define BCAP2     4608                    // per-bucket cap: mean 4092 + 8 sigma
#define PREA_BLKS 800
#define EPBA      (N_EDGES / PREA_BLKS)   // 2000 edges per block
#define PRE_BLKS  (PREA_BLKS + 48)        // + W-prep blocks
#define GEMM1_BLKS 782

typedef __attribute__((ext_vector_type(8))) short bf16x8;
typedef __attribute__((ext_vector_type(4))) float f32x4;
typedef __attribute__((ext_vector_type(8))) float f32x8;
typedef __attribute__((ext_vector_type(4))) int   i32x4;

__device__ inline unsigned short f2bf_u(float x) {
    __hip_bfloat16 h = __float2bfloat16(x);
    return __builtin_bit_cast(unsigned short, h);
}
__device__ inline float bfu2f(unsigned short u) {
    unsigned v = ((unsigned)u) << 16;
    return __builtin_bit_cast(float, v);
}

// ---------------- W prep helper ----------------
__device__ inline void prep_pack(const float* __restrict__ Wl,
                                 const float* __restrict__ Wr,
                                 ushort2* __restrict__ Bhi,
                                 ushort2* __restrict__ Blo, int idx) {
    int j  = idx & 3;
    int l  = (idx >> 2) & 63;
    int c  = (idx >> 8) & 7;
    int kt = idx >> 11;
    int col = c * 16 + (l & 15);
    int k0  = kt * 32 + (l >> 4) * 8 + 2 * j;
    const float* W = (col < 64) ? Wl : Wr;
    int cc = col & 63;
    float w0 = W[(size_t)k0 * 64 + cc];
    float w1 = W[(size_t)(k0 + 1) * 64 + cc];
    unsigned short h0 = f2bf_u(w0), h1 = f2bf_u(w1);
    unsigned short lo0 = f2bf_u(w0 - bfu2f(h0)), lo1 = f2bf_u(w1 - bfu2f(h1));
    Bhi[idx] = make_ushort2(h0, h1);
    Blo[idx] = make_ushort2(lo0, lo1);
}

// ---------------- phase A: fine-bucket edges (read once, LDS-aggregated) + W prep ------
__global__ __launch_bounds__(256) void k_pre(const int* __restrict__ ei,
                                             int* __restrict__ gcnt,
                                             uint2* __restrict__ ebuf,
                                             const float* __restrict__ W1l,
                                             const float* __restrict__ W1r,
                                             const float* __restrict__ W2l,
                                             const float* __restrict__ W2r,
                                             ushort2* __restrict__ Bh1,
                                             ushort2* __restrict__ Bl1,
                                             ushort2* __restrict__ Bh2,
                                             ushort2* __restrict__ Bl2) {
    if (blockIdx.x >= PREA_BLKS) {
        int bb = blockIdx.x - PREA_BLKS;
        if (bb < 32) prep_pack(W1l, W1r, Bh1, Bl1, bb * 256 + threadIdx.x);
        else         prep_pack(W2l, W2r, Bh2, Bl2, (bb - 32) * 256 + threadIdx.x);
        return;
    }
    __shared__ int hist[NBKT], gbase[NBKT];
    const int tid = threadIdx.x;
    for (int i = tid; i < NBKT; i += 256) hist[i] = 0;
    __syncthreads();
    const int start = blockIdx.x * EPBA;
    const int end   = start + EPBA;
    const int* __restrict__ src = ei;
    const int* __restrict__ dst = ei + N_EDGES;
    // pass 1: LDS histogram (chunk is small: 8KB, stays L2-hot for pass 2)
    for (int i = start + tid; i < end; i += 256)
        atomicAdd(&hist[dst[i] >> 8], 1);
    __syncthreads();
    // one bulk reservation per non-empty bucket; reuse hist as local cursor
    for (int i = tid; i < NBKT; i += 256) {
        int h = hist[i];
        gbase[i] = (h > 0) ? atomicAdd(&gcnt[i], h) : 0;
        hist[i] = 0;
    }
    __syncthreads();
    // pass 2: ranked writes -> per-block contiguous runs inside each bucket segment
    for (int i = start + tid; i < end; i += 256) {
        int d = dst[i];
        int s = src[i];
        int b = d >> 8;
        int r = gbase[b] + atomicAdd(&hist[b], 1);
        if (r < BCAP2) ebuf[(size_t)b * BCAP2 + r] = make_uint2((unsigned)d, (unsigned)s);
    }
}

// ---------------- phase B: per-bucket padded-adj build in LDS, coalesced write-out -----
__global__ __launch_bounds__(256) void k_preB(const int* __restrict__ gcnt,
                                              const uint2* __restrict__ ebuf,
                                              int* __restrict__ adj,
                                              int* __restrict__ deg) {
    __shared__ int adjL[256 * PSTRIDE];   // 49152 B
    __shared__ int degL[256];
    const int b   = blockIdx.x;
    const int tid = threadIdx.x;
    degL[tid] = 0;
    __syncthreads();
    const int cnt  = min(gcnt[b], BCAP2);
    const int base = b << 8;
    const uint2* __restrict__ eb = ebuf + (size_t)b * BCAP2;
    for (int i = tid; i < cnt; i += 256) {
        uint2 p = eb[i];
        int r = (int)p.x - base;          // 0..255
        int pos = atomicAdd(&degL[r], 1);
        if (pos < PSTRIDE) adjL[r * PSTRIDE + pos] = (int)p.y;
    }
    __syncthreads();
    const int node = base + tid;
    if (node < N_NODES) deg[node] = degL[tid];
    // coalesced tile write: each 64B line written exactly once
    i32x4* __restrict__ dstp = (i32x4*)(adj + (size_t)base * PSTRIDE);
    const i32x4* __restrict__ srcp = (const i32x4*)adjL;
    for (int i = tid; i < 256 * PSTRIDE / 4; i += 256)
        dstp[i] = srcp[i];
}

// ---------------- GEMM1: [Abf|Dbf] = X[n x 128] @ [W1l|W1r] (3-term bf16 split) --------
__global__ __launch_bounds__(256) void k_gemm1(const float* __restrict__ X,
                                               const i32x4* __restrict__ Bhi,
                                               const i32x4* __restrict__ Blo,
                                               const float* __restrict__ bias,
                                               unsigned short* __restrict__ Ybf,
                                               unsigned short* __restrict__ Dbf, int n) {
    const int K = IN_DIM;
    const int lane = threadIdx.x & 63;
    const int wid  = threadIdx.x >> 6;
    const int m0   = (blockIdx.x * 4 + wid) * 32;
    if (m0 >= n) return;
    const int r  = lane & 15;
    const int kg = lane >> 4;

    f32x4 acc[2][8];
#pragma unroll
    for (int mt = 0; mt < 2; ++mt)
#pragma unroll
        for (int c = 0; c < 8; ++c) acc[mt][c] = (f32x4)(0.f);

#pragma unroll
    for (int kt = 0; kt < K / 32; ++kt) {
        bf16x8 ah[2], al[2];
#pragma unroll
        for (int mt = 0; mt < 2; ++mt) {
            const f32x4* p = (const f32x4*)(X + (size_t)(m0 + mt * 16 + r) * K + kt * 32 + kg * 8);
            f32x4 x0 = __builtin_nontemporal_load(p);
            f32x4 x1 = __builtin_nontemporal_load(p + 1);
            float xv[8];
#pragma unroll
            for (int t = 0; t < 4; ++t) { xv[t] = x0[t]; xv[4 + t] = x1[t]; }
#pragma unroll
            for (int t = 0; t < 8; ++t) {
                unsigned short h = f2bf_u(xv[t]);
                ah[mt][t] = (short)h;
                al[mt][t] = (short)f2bf_u(xv[t] - bfu2f(h));
            }
        }
#pragma unroll
        for (int c = 0; c < 8; ++c) {
            const int bi = (kt * 8 + c) * 64 + lane;
            bf16x8 bh = __builtin_bit_cast(bf16x8, Bhi[bi]);
            bf16x8 bl = __builtin_bit_cast(bf16x8, Blo[bi]);
#pragma unroll
            for (int mt = 0; mt < 2; ++mt) {
                acc[mt][c] = __builtin_amdgcn_mfma_f32_16x16x32_bf16(ah[mt], bh, acc[mt][c], 0, 0, 0);
                acc[mt][c] = __builtin_amdgcn_mfma_f32_16x16x32_bf16(ah[mt], bl, acc[mt][c], 0, 0, 0);
                acc[mt][c] = __builtin_amdgcn_mfma_f32_16x16x32_bf16(al[mt], bh, acc[mt][c], 0, 0, 0);
            }
        }
    }
#pragma unroll
    for (int mt = 0; mt < 2; ++mt) {
#pragma unroll
        for (int c = 0; c < 8; ++c) {
            int col = c * 16 + r;
            float badd = (c >= 4) ? bias[col - 64] : 0.f;
#pragma unroll
            for (int j = 0; j < 4; ++j) {
                int row = m0 + mt * 16 + kg * 4 + j;
                if (row < n) {
                    if (c < 4) Ybf[(size_t)row * 64 + col] = f2bf_u(acc[mt][c][j]);
                    else       Dbf[(size_t)row * 64 + col - 64] = f2bf_u(acc[mt][c][j] + badd);
                }
            }
        }
    }
}

// ---------------- fused agg1 + gemm2: block = 32 nodes; 16B/lane gathers --------------
__global__ __launch_bounds__(256) void k_agg1f(const unsigned short* __restrict__ Abf,
                                               unsigned short* __restrict__ Dbf,
                                               const int* __restrict__ adj,
                                               const int* __restrict__ deg,
                                               const i32x4* __restrict__ Bhi,
                                               const i32x4* __restrict__ Blo,
                                               const float* __restrict__ bias,
                                               unsigned short* __restrict__ Bbf) {
    __shared__ unsigned short hs[32][72];
    const int lane = threadIdx.x & 63;
    const int wv   = threadIdx.x >> 6;
    const int v0   = blockIdx.x * 32;
    const int c = lane & 7;
    const int j = lane >> 3;
    const bf16x8* __restrict__ A8 = (const bf16x8*)Abf;

    for (int t = 0; t < 8; ++t) {
        const int v = v0 + wv * 8 + t;
        const int s = v * PSTRIDE;
        const int dgf = deg[v];
        const int d = min(dgf, PSTRIDE);
        const float iv = 1.0f / (float)max(dgf, 1);
        const int uall = (lane < d) ? adj[s + lane] : 0;
        f32x8 acc = (f32x8)(0.f);
        const int nit = (d + 7) >> 3;
        for (int it = 0; it < nit; ++it) {
            const int nb = it * 8 + j;
            const int u = __shfl(uall, nb, 64);
            if (nb < d) {
                bf16x8 m = A8[(size_t)u * 8 + c];
#pragma unroll
                for (int q = 0; q < 8; ++q) acc[q] += bfu2f((unsigned short)m[q]);
            }
        }
#pragma unroll
        for (int msk = 8; msk <= 32; msk <<= 1) {
#pragma unroll
            for (int q = 0; q < 8; ++q) acc[q] += __shfl_xor(acc[q], msk, 64);
        }
        if (j == 0) {
            bf16x8 zb = ((const bf16x8*)Dbf)[(size_t)v * 8 + c];
            bf16x8 hb;
#pragma unroll
            for (int q = 0; q < 8; ++q)
                hb[q] = (short)f2bf_u(fmaxf(fmaf(acc[q], iv, bfu2f((unsigned short)zb[q])), 0.f));
            *(bf16x8*)&hs[wv * 8 + t][c * 8] = hb;
        }
    }
    __syncthreads();
    const int r  = lane & 15;
    const int kg = lane >> 4;
    f32x4 acc2[2][2];
#pragma unroll
    for (int mt = 0; mt < 2; ++mt)
#pragma unroll
        for (int ci = 0; ci < 2; ++ci) acc2[mt][ci] = (f32x4)(0.f);
#pragma unroll
    for (int kt = 0; kt < 2; ++kt) {
        bf16x8 ah[2];
#pragma unroll
        for (int mt = 0; mt < 2; ++mt)
            ah[mt] = *(const bf16x8*)&hs[mt * 16 + r][kt * 32 + kg * 8];
#pragma unroll
        for (int ci = 0; ci < 2; ++ci) {
            const int cg = wv * 2 + ci;
            const int bi = (kt * 8 + cg) * 64 + lane;
            bf16x8 bh = __builtin_bit_cast(bf16x8, Bhi[bi]);
            bf16x8 bl = __builtin_bit_cast(bf16x8, Blo[bi]);
#pragma unroll
            for (int mt = 0; mt < 2; ++mt) {
                acc2[mt][ci] = __builtin_amdgcn_mfma_f32_16x16x32_bf16(ah[mt], bh, acc2[mt][ci], 0, 0, 0);
                acc2[mt][ci] = __builtin_amdgcn_mfma_f32_16x16x32_bf16(ah[mt], bl, acc2[mt][ci], 0, 0, 0);
            }
        }
    }
#pragma unroll
    for (int mt = 0; mt < 2; ++mt) {
#pragma unroll
        for (int ci = 0; ci < 2; ++ci) {
            const int cg = wv * 2 + ci;
            const int col = cg * 16 + r;
            const float badd = (cg >= 4) ? bias[col - 64] : 0.f;
#pragma unroll
            for (int jj = 0; jj < 4; ++jj) {
                const int row = v0 + mt * 16 + kg * 4 + jj;
                if (cg < 4) Bbf[(size_t)row * 64 + col] = f2bf_u(acc2[mt][ci][jj]);
                else        Dbf[(size_t)row * 64 + col - 64] = f2bf_u(acc2[mt][ci][jj] + badd);
            }
        }
    }
}

// ---------------- final agg: out = relu(sum(Bbf[adj])/deg + Dbf) @ Wc + bc ------------
__global__ __launch_bounds__(256) void k_agg2(const unsigned short* __restrict__ Abf,
                                              const unsigned short* __restrict__ Zbf,
                                              const int* __restrict__ adj,
                                              const int* __restrict__ deg,
                                              const float* __restrict__ Wc,
                                              const float* __restrict__ bc,
                                              float* __restrict__ out, int n) {
    const int lane = threadIdx.x & 63;
    const int wv = threadIdx.x >> 6;
    const int v = blockIdx.x * 4 + wv;
    if (v >= n) return;
    const int c = lane & 7;
    const int j = lane >> 3;
    const int s = v * PSTRIDE;
    const int dgf = deg[v];
    const int d = min(dgf, PSTRIDE);
    const float iv = 1.0f / (float)max(dgf, 1);
    const int uall = (lane < d) ? adj[s + lane] : 0;
    f32x8 acc = (f32x8)(0.f);
    const bf16x8* __restrict__ A8 = (const bf16x8*)Abf;
    const int nit = (d + 7) >> 3;
    for (int it = 0; it < nit; ++it) {
        const int nb = it * 8 + j;
        const int u = __shfl(uall, nb, 64);
        if (nb < d) {
            bf16x8 m = A8[(size_t)u * 8 + c];
#pragma unroll
            for (int q = 0; q < 8; ++q) acc[q] += bfu2f((unsigned short)m[q]);
        }
    }
#pragma unroll
    for (int msk = 8; msk <= 32; msk <<= 1) {
#pragma unroll
        for (int q = 0; q < 8; ++q) acc[q] += __shfl_xor(acc[q], msk, 64);
    }
    bf16x8 zb = ((const bf16x8*)Zbf)[(size_t)v * 8 + c];
    const float4* Wc4 = (const float4*)Wc;
    float4 w0 = Wc4[c * 2], w1 = Wc4[c * 2 + 1];
    float h;
    float pv = 0.f;
    h = fmaxf(fmaf(acc[0], iv, bfu2f((unsigned short)zb[0])), 0.f); pv += h * w0.x;
    h = fmaxf(fmaf(acc[1], iv, bfu2f((unsigned short)zb[1])), 0.f); pv += h * w0.y;
    h = fmaxf(fmaf(acc[2], iv, bfu2f((unsigned short)zb[2])), 0.f); pv += h * w0.z;
    h = fmaxf(fmaf(acc[3], iv, bfu2f((unsigned short)zb[3])), 0.f); pv += h * w0.w;
    h = fmaxf(fmaf(acc[4], iv, bfu2f((unsigned short)zb[4])), 0.f); pv += h * w1.x;
    h = fmaxf(fmaf(acc[5], iv, bfu2f((unsigned short)zb[5])), 0.f); pv += h * w1.y;
    h = fmaxf(fmaf(acc[6], iv, bfu2f((unsigned short)zb[6])), 0.f); pv += h * w1.z;
    h = fmaxf(fmaf(acc[7], iv, bfu2f((unsigned short)zb[7])), 0.f); pv += h * w1.w;
#pragma unroll
    for (int msk = 1; msk <= 4; msk <<= 1) pv += __shfl_xor(pv, msk, 64);
    if (lane == 0) out[v] = pv + bc[0];
}

extern "C" void kernel_launch(void* const* d_in, const int* in_sizes, int n_in,
                              void* d_out, int out_size, void* d_ws, size_t ws_size,
                              hipStream_t stream) {
    const float* x   = (const float*)d_in[0];
    const int*   ei  = (const int*)d_in[1];
    const float* W1l = (const float*)d_in[2];
    const float* W1r = (const float*)d_in[3];
    const float* b1  = (const float*)d_in[4];
    const float* W2l = (const float*)d_in[5];
    const float* W2r = (const float*)d_in[6];
    const float* b2  = (const float*)d_in[7];
    const float* Wc  = (const float*)d_in[8];
    const float* bc  = (const float*)d_in[9];
    float* out = (float*)d_out;

    char* w = (char*)d_ws;
    auto carve = [&](size_t bytes) -> void* {
        void* p = (void*)w;
        w += (bytes + 255) & ~(size_t)255;
        return p;
    };
    int* gcnt = (int*)carve((size_t)NBKT * 4);
    int* deg  = (int*)carve((size_t)N_NODES * 4);
    int* adj  = (int*)carve((size_t)(N_NODES + 256) * PSTRIDE * 4);   // +256-node slack (last bucket)
    unsigned short* Abf = (unsigned short*)carve((size_t)N_NODES * HID * 2);
    unsigned short* Bbf = (unsigned short*)carve((size_t)N_NODES * HID * 2);
    unsigned short* Dbf = (unsigned short*)carve((size_t)N_NODES * HID * 2);
    uint2* ebuf = (uint2*)carve((size_t)NBKT * BCAP2 * 8);            // 14.4 MB
    ushort2* Bh1 = (ushort2*)carve((size_t)(IN_DIM / 32) * 8 * 64 * 4 * 4);
    ushort2* Bl1 = (ushort2*)carve((size_t)(IN_DIM / 32) * 8 * 64 * 4 * 4);
    ushort2* Bh2 = (ushort2*)carve((size_t)(HID / 32) * 8 * 64 * 4 * 4);
    ushort2* Bl2 = (ushort2*)carve((size_t)(HID / 32) * 8 * 64 * 4 * 4);

    hipMemsetAsync(gcnt, 0, (size_t)NBKT * 4, stream);

    // phase A bucketing + W prep
    k_pre<<<PRE_BLKS, 256, 0, stream>>>(ei, gcnt, ebuf, W1l, W1r, W2l, W2r, Bh1, Bl1, Bh2, Bl2);
    // phase B: LDS-staged padded adjacency (coalesced write-out) + deg
    k_preB<<<NBKT, 256, 0, stream>>>(gcnt, ebuf, adj, deg);
    // GEMM1
    k_gemm1<<<GEMM1_BLKS, 256, 0, stream>>>(x, (const i32x4*)Bh1, (const i32x4*)Bl1, b1, Abf, Dbf, N_NODES);
    // fused agg1 + gemm2
    k_agg1f<<<N_NODES / 32, 256, 0, stream>>>(Abf, Dbf, adj, deg,
                                              (const i32x4*)Bh2, (const i32x4*)Bl2, b2, Bbf);
    // final agg + classifier head
    k_agg2<<<N_NODES / 4, 256, 0, stream>>>(Bbf, Dbf, adj, deg, Wc, bc, out, N_NODES);
}